// Round 5
// baseline (112.287 us; speedup 1.0000x reference)
//
#include <hip/hip_runtime.h>
#include <hip/hip_bf16.h>
#include <math.h>

typedef _Float16 f16;
typedef __attribute__((ext_vector_type(8))) _Float16 f16x8;
typedef __attribute__((ext_vector_type(4))) _Float16 f16x4;
typedef __attribute__((ext_vector_type(4))) float f32x4;

#define S_LEN 4096
#define NHEAD 8
#define HDIM 64
#define EMB 512
#define KDIM 512
#define LOG2E 1.4426950408889634f

#if __has_builtin(__builtin_amdgcn_exp2f)
#define EXP2F(x) __builtin_amdgcn_exp2f(x)
#else
#define EXP2F(x) exp2f(x)
#endif

// ---------------- cast / transpose ----------------
__global__ void cast_f32_f16_kernel(const float* __restrict__ in, f16* __restrict__ out, int n) {
  int i = (blockIdx.x * 256 + threadIdx.x) * 4;
  if (i >= n) return;
  float4 v = *(const float4*)(in + i);
  f16x4 o = { (f16)v.x, (f16)v.y, (f16)v.z, (f16)v.w };
  *(f16x4*)(out + i) = o;
}

// in [R][C] f32  ->  out [C][R] f16
__global__ void transpose_cast_kernel(const float* __restrict__ in, f16* __restrict__ out, int R, int C) {
  int idx = blockIdx.x * 256 + threadIdx.x;
  if (idx >= R * C) return;
  int r = idx / C, c = idx - r * C;
  out[(size_t)c * R + r] = (f16)in[idx];
}

// ---------------- GEMM: C[M][N] = A[M][K] * Bt[N][K]^T + bias ----------------
#define TM 128
#define TN 128
#define TK 32
#define LDP 40  // padded LDS row; 80 B = 5*16 B so 16B accesses stay aligned

template<int MODE>
__global__ __launch_bounds__(256) void gemm_bt_kernel(
    const f16* __restrict__ A, const f16* __restrict__ Bt, const float* __restrict__ bias,
    f16* __restrict__ Qo, f16* __restrict__ Ko, f16* __restrict__ Vo,
    float* __restrict__ Co, int M, int N) {
  __shared__ f16 As[TM][LDP];
  __shared__ f16 Bs[TN][LDP];
  const int m0 = blockIdx.x * TM, n0 = blockIdx.y * TN;
  const int tid = threadIdx.x;
  const int lane = tid & 63, wid = tid >> 6;
  const int wr = wid >> 1, wc = wid & 1;      // 2x2 wave grid, each wave 64x64
  const int g = lane >> 4, q16 = lane & 15;
  const int sr = tid >> 1, sh = tid & 1;      // staging: row, 16-elem half

  f32x4 zero = {0.f, 0.f, 0.f, 0.f};
  f32x4 acc[4][4];
#pragma unroll
  for (int i = 0; i < 4; i++)
#pragma unroll
    for (int j = 0; j < 4; j++) acc[i][j] = zero;

  for (int kk = 0; kk < KDIM; kk += TK) {
    const f16* Ap = A + (size_t)(m0 + sr) * KDIM + kk + sh * 16;
    const f16* Bp = Bt + (size_t)(n0 + sr) * KDIM + kk + sh * 16;
    int4 av0 = *(const int4*)(Ap);
    int4 av1 = *(const int4*)(Ap + 8);
    int4 bv0 = *(const int4*)(Bp);
    int4 bv1 = *(const int4*)(Bp + 8);
    *(int4*)&As[sr][sh * 16]     = av0;
    *(int4*)&As[sr][sh * 16 + 8] = av1;
    *(int4*)&Bs[sr][sh * 16]     = bv0;
    *(int4*)&Bs[sr][sh * 16 + 8] = bv1;
    __syncthreads();
    f16x8 af[4], bfr[4];
#pragma unroll
    for (int i = 0; i < 4; i++) af[i] = *(const f16x8*)&As[wr * 64 + i * 16 + q16][8 * g];
#pragma unroll
    for (int j = 0; j < 4; j++) bfr[j] = *(const f16x8*)&Bs[wc * 64 + j * 16 + q16][8 * g];
#pragma unroll
    for (int i = 0; i < 4; i++)
#pragma unroll
      for (int j = 0; j < 4; j++)
        acc[i][j] = __builtin_amdgcn_mfma_f32_16x16x32_f16(af[i], bfr[j], acc[i][j], 0, 0, 0);
    __syncthreads();
  }

#pragma unroll
  for (int i = 0; i < 4; i++)
#pragma unroll
    for (int j = 0; j < 4; j++) {
      const int n = n0 + wc * 64 + j * 16 + q16;
      const float bs = bias[n];
      const int mbase = m0 + wr * 64 + i * 16 + 4 * g;
      if (MODE == 1) {
#pragma unroll
        for (int r = 0; r < 4; r++) Co[(size_t)(mbase + r) * N + n] = acc[i][j][r] + bs;
      } else {
        const int b = mbase >> 12, s = mbase & (S_LEN - 1);
        const int h = n / 192, rr = n - h * 192;
        const size_t bh = (size_t)b * NHEAD + h;
        if (rr < 64) {
#pragma unroll
          for (int r = 0; r < 4; r++)
            Qo[(bh * S_LEN + s + r) * HDIM + rr] = (f16)((acc[i][j][r] + bs) * 0.125f);
        } else if (rr < 128) {
#pragma unroll
          for (int r = 0; r < 4; r++)
            Ko[(bh * S_LEN + s + r) * HDIM + (rr - 64)] = (f16)(acc[i][j][r] + bs);
        } else {
          f16x4 vv = { (f16)(acc[i][j][0] + bs), (f16)(acc[i][j][1] + bs),
                       (f16)(acc[i][j][2] + bs), (f16)(acc[i][j][3] + bs) };
          *(f16x4*)(Vo + (bh * HDIM + (rr - 128)) * S_LEN + s) = vv;  // V^T
        }
      }
    }
}

// ---------------- sliding-window flash attention (split-K) ----------------
// Q,K: [bh][s][64] f16 (Q pre-scaled by 1/8); Vt: [bh][64][s] f16; out: [b][s][512] f16
// Block = 32 queries. Waves 0,1: queries [qw,qw+16),[qw+16,qw+32), key tiles 0..4.
// Waves 2,3: same queries, key tiles 5..8. Merge halves via LDS in epilogue.
// 8192 waves total -> ~28-32 waves/CU (2x TLP vs round 4).
__global__ __launch_bounds__(256, 4) void attn_kernel(
    const f16* __restrict__ Q, const f16* __restrict__ K,
    const f16* __restrict__ Vt, f16* __restrict__ O) {
  __shared__ float oS[2][64][16];
  __shared__ float lS[2][64];
  __shared__ float mS[2][64];

  const int wg = blockIdx.x;
  const int v = (wg & 7) * 256 + (wg >> 3);   // XCD swizzle: each XCD owns 2 whole bh
  const int bh = v >> 7, qc = v & 127;        // 32-query chunk
  const int b = bh >> 3, h = bh & 7;
  const int wid = threadIdx.x >> 6, lane = threadIdx.x & 63;
  const int g = lane >> 4, q16 = lane & 15;
  const int qw = qc * 32 + (wid & 1) * 16;    // this wave's 16 queries
  const int kh = wid >> 1;                    // key half: 0 -> tiles 0..4, 1 -> tiles 5..8
  const int qg = qw + q16;                    // query this lane's softmax state tracks

  const f16* Qb = Q + ((size_t)bh * S_LEN + qw) * HDIM;
  f16x8 qf0 = *(const f16x8*)(Qb + q16 * HDIM + 8 * g);        // d 0..31
  f16x8 qf1 = *(const f16x8*)(Qb + q16 * HDIM + 32 + 8 * g);   // d 32..63

  const f16* Kbase = K + (size_t)bh * S_LEN * HDIM;
  const f16* Vbase = Vt + (size_t)bh * HDIM * S_LEN;

  f32x4 zero = {0.f, 0.f, 0.f, 0.f};
  f32x4 o[4];
#pragma unroll
  for (int dt = 0; dt < 4; dt++) o[dt] = zero;
  float m_run = 0.f;   // static base: logits ~N(0,1); vote-guarded rescale if exceeded by 8
  float l_run = 0.f;   // per-lane partial; reduced in epilogue

  const int t0 = kh ? 5 : 0;
  const int t1 = kh ? 9 : 5;
  for (int t = t0; t < t1; ++t) {
    const int kA = qw - 128 + 32 * t;   // 16-aligned -> chunks fully in or fully out
    const int kB = kA + 16;
    const int cA = min(max(kA, 0), S_LEN - 16);  // clamp: OOB chunks read valid mem, masked
    const int cB = min(max(kB, 0), S_LEN - 16);
    const f16* KA = Kbase + (size_t)(cA + q16) * HDIM + 8 * g;
    const f16* KB = Kbase + (size_t)(cB + q16) * HDIM + 8 * g;
    f16x8 ka0 = *(const f16x8*)(KA);
    f16x8 ka1 = *(const f16x8*)(KA + 32);
    f16x8 kb0 = *(const f16x8*)(KB);
    f16x8 kb1 = *(const f16x8*)(KB + 32);
    f16x4 va[4], vb[4];
#pragma unroll
    for (int dt = 0; dt < 4; dt++) {
      const f16* Vr = Vbase + (size_t)(dt * 16 + q16) * S_LEN;
      va[dt] = *(const f16x4*)(Vr + cA + 4 * g);
      vb[dt] = *(const f16x4*)(Vr + cB + 4 * g);
    }

    f32x4 sA = zero, sB = zero;
    sA = __builtin_amdgcn_mfma_f32_16x16x32_f16(ka0, qf0, sA, 0, 0, 0);
    sA = __builtin_amdgcn_mfma_f32_16x16x32_f16(ka1, qf1, sA, 0, 0, 0);
    sB = __builtin_amdgcn_mfma_f32_16x16x32_f16(kb0, qf0, sB, 0, 0, 0);
    sB = __builtin_amdgcn_mfma_f32_16x16x32_f16(kb1, qf1, sB, 0, 0, 0);

    // mask (window + range); lane-local max only
    float sv[8];
    float mx = -INFINITY;
#pragma unroll
    for (int i = 0; i < 4; i++) {
      const int kgA = kA + 4 * g + i;
      const int kgB = kB + 4 * g + i;
      const bool okA = ((unsigned)(kgA - qg + 128) <= 256u) && ((unsigned)kgA < S_LEN);
      const bool okB = ((unsigned)(kgB - qg + 128) <= 256u) && ((unsigned)kgB < S_LEN);
      sv[i]     = okA ? sA[i] : -INFINITY;
      sv[i + 4] = okB ? sB[i] : -INFINITY;
      mx = fmaxf(mx, fmaxf(sv[i], sv[i + 4]));
    }

    // speculative p = exp(sv - m_run); corrected on the (~never) cold path
    float pA[4], pB[4];
#pragma unroll
    for (int i = 0; i < 4; i++) {
      pA[i] = EXP2F((sv[i] - m_run) * LOG2E);
      pB[i] = EXP2F((sv[i + 4] - m_run) * LOG2E);
    }

    if (__builtin_expect(!__all(mx - m_run <= 8.f), 0)) {
      float mxq = fmaxf(mx, __shfl_xor(mx, 16));
      mxq = fmaxf(mxq, __shfl_xor(mxq, 32));
      const float mnew = fmaxf(m_run, mxq);
      const float resc = EXP2F((m_run - mnew) * LOG2E);   // per query q16
#pragma unroll
      for (int i = 0; i < 4; i++) { pA[i] *= resc; pB[i] *= resc; }
      l_run *= resc;
      float ri[4];
#pragma unroll
      for (int i = 0; i < 4; i++) ri[i] = __shfl(resc, 4 * g + i);  // per query 4g+i
#pragma unroll
      for (int dt = 0; dt < 4; dt++)
#pragma unroll
        for (int i = 0; i < 4; i++) o[dt][i] *= ri[i];
      m_run = mnew;
    }

    f16x4 pfA, pfB;
#pragma unroll
    for (int i = 0; i < 4; i++) {
      l_run += pA[i] + pB[i];
      pfA[i] = (f16)pA[i];
      pfB[i] = (f16)pB[i];
    }

#pragma unroll
    for (int dt = 0; dt < 4; dt++) {
      o[dt] = __builtin_amdgcn_mfma_f32_16x16x16f16(pfA, va[dt], o[dt], 0, 0, 0);
      o[dt] = __builtin_amdgcn_mfma_f32_16x16x16f16(pfB, vb[dt], o[dt], 0, 0, 0);
    }
  }

  // reduce l across the 4 g-groups (same query q16)
  l_run += __shfl_xor(l_run, 16);
  l_run += __shfl_xor(l_run, 32);

  // ---- split-K merge: waves 2,3 publish; waves 0,1 combine + store ----
  if (wid >= 2) {
#pragma unroll
    for (int dt = 0; dt < 4; dt++)
#pragma unroll
      for (int i = 0; i < 4; i++) oS[wid - 2][lane][dt * 4 + i] = o[dt][i];
    lS[wid - 2][lane] = l_run;
    mS[wid - 2][lane] = m_run;
  }
  __syncthreads();
  if (wid < 2) {
    const float mB = mS[wid][lane];
    const float lB = lS[wid][lane];
    const float m = fmaxf(m_run, mB);
    const float fA = EXP2F((m_run - m) * LOG2E);
    const float fB = EXP2F((mB - m) * LOG2E);
    const float linv = 1.f / (l_run * fA + lB * fB);
    const float aA = fA * linv, aB = fB * linv;   // per query q16
    float aAi[4], aBi[4];
#pragma unroll
    for (int i = 0; i < 4; i++) {
      aAi[i] = __shfl(aA, 4 * g + i);             // per query 4g+i
      aBi[i] = __shfl(aB, 4 * g + i);
    }
#pragma unroll
    for (int dt = 0; dt < 4; dt++)
#pragma unroll
      for (int i = 0; i < 4; i++) {
        const float ov = o[dt][i] * aAi[i] + oS[wid][lane][dt * 4 + i] * aBi[i];
        const int s_idx = qw + 4 * g + i;
        O[((size_t)b * S_LEN + s_idx) * EMB + h * HDIM + dt * 16 + q16] = (f16)ov;
      }
  }
}

// ---------------- launch ----------------
extern "C" void kernel_launch(void* const* d_in, const int* in_sizes, int n_in,
                              void* d_out, int out_size, void* d_ws, size_t ws_size,
                              hipStream_t stream) {
  const float* x     = (const float*)d_in[0];
  const float* w_qkv = (const float*)d_in[1];
  const float* b_qkv = (const float*)d_in[2];
  const float* w_o   = (const float*)d_in[3];
  const float* b_o   = (const float*)d_in[4];
  float* out = (float*)d_out;

  char* ws = (char*)d_ws;
  f16* xb    = (f16*)(ws);                 // [8192][512]        8.0 MiB
  f16* wqkvt = (f16*)(ws + 8388608);       // [1536][512]        1.5 MiB
  f16* wot   = (f16*)(ws + 9961472);       // [512][512]         0.5 MiB
  f16* Qs    = (f16*)(ws + 10485760);      // [16][4096][64]     8 MiB
  f16* Ks    = (f16*)(ws + 18874368);      // [16][4096][64]     8 MiB
  f16* Vt    = (f16*)(ws + 27262976);      // [16][64][4096]     8 MiB
  f16* attn  = (f16*)(ws + 35651584);      // [8192][512]        8 MiB

  cast_f32_f16_kernel<<<4096, 256, 0, stream>>>(x, xb, 8192 * 512);
  transpose_cast_kernel<<<3072, 256, 0, stream>>>(w_qkv, wqkvt, 512, 1536);
  transpose_cast_kernel<<<1024, 256, 0, stream>>>(w_o, wot, 512, 512);
  gemm_bt_kernel<0><<<dim3(64, 12), 256, 0, stream>>>(xb, wqkvt, b_qkv, Qs, Ks, Vt,
                                                      (float*)nullptr, 8192, 1536);
  attn_kernel<<<2048, 256, 0, stream>>>(Qs, Ks, Vt, attn);
  gemm_bt_kernel<1><<<dim3(64, 4), 256, 0, stream>>>(attn, wot, b_o,
                                                     (f16*)nullptr, (f16*)nullptr, (f16*)nullptr,
                                                     out, 8192, 512);
}

// Round 7
// 78.191 us; speedup vs baseline: 1.4361x; 1.4361x over previous
//
#include <hip/hip_runtime.h>
#include <hip/hip_bf16.h>
#include <math.h>

typedef _Float16 f16;
typedef __attribute__((ext_vector_type(8))) _Float16 f16x8;
typedef __attribute__((ext_vector_type(4))) _Float16 f16x4;
typedef __attribute__((ext_vector_type(4))) float f32x4;

#define S_LEN 4096
#define NHEAD 8
#define HDIM 64
#define EMB 512
#define KDIM 512
#define LOG2E 1.4426950408889634f

#if __has_builtin(__builtin_amdgcn_exp2f)
#define EXP2F(x) __builtin_amdgcn_exp2f(x)
#else
#define EXP2F(x) exp2f(x)
#endif

// ---------------- cast / transpose ----------------
__global__ void cast_f32_f16_kernel(const float* __restrict__ in, f16* __restrict__ out, int n) {
  int i = (blockIdx.x * 256 + threadIdx.x) * 4;
  if (i >= n) return;
  float4 v = *(const float4*)(in + i);
  f16x4 o = { (f16)v.x, (f16)v.y, (f16)v.z, (f16)v.w };
  *(f16x4*)(out + i) = o;
}

// in [R][C] f32  ->  out [C][R] f16
__global__ void transpose_cast_kernel(const float* __restrict__ in, f16* __restrict__ out, int R, int C) {
  int idx = blockIdx.x * 256 + threadIdx.x;
  if (idx >= R * C) return;
  int r = idx / C, c = idx - r * C;
  out[(size_t)c * R + r] = (f16)in[idx];
}

// ---------------- GEMM: C[M][N] = A[M][K] * Bt[N][K]^T + bias ----------------
#define TM 128
#define TN 128
#define TK 32
#define LDP 40  // padded LDS row; 80 B = 5*16 B so 16B accesses stay aligned

template<int MODE>
__global__ __launch_bounds__(256) void gemm_bt_kernel(
    const f16* __restrict__ A, const f16* __restrict__ Bt, const float* __restrict__ bias,
    f16* __restrict__ Qo, f16* __restrict__ Ko, f16* __restrict__ Vo,
    float* __restrict__ Co, int M, int N) {
  __shared__ f16 As[TM][LDP];
  __shared__ f16 Bs[TN][LDP];
  const int m0 = blockIdx.x * TM, n0 = blockIdx.y * TN;
  const int tid = threadIdx.x;
  const int lane = tid & 63, wid = tid >> 6;
  const int wr = wid >> 1, wc = wid & 1;      // 2x2 wave grid, each wave 64x64
  const int g = lane >> 4, q16 = lane & 15;
  const int sr = tid >> 1, sh = tid & 1;      // staging: row, 16-elem half

  f32x4 zero = {0.f, 0.f, 0.f, 0.f};
  f32x4 acc[4][4];
#pragma unroll
  for (int i = 0; i < 4; i++)
#pragma unroll
    for (int j = 0; j < 4; j++) acc[i][j] = zero;

  for (int kk = 0; kk < KDIM; kk += TK) {
    const f16* Ap = A + (size_t)(m0 + sr) * KDIM + kk + sh * 16;
    const f16* Bp = Bt + (size_t)(n0 + sr) * KDIM + kk + sh * 16;
    int4 av0 = *(const int4*)(Ap);
    int4 av1 = *(const int4*)(Ap + 8);
    int4 bv0 = *(const int4*)(Bp);
    int4 bv1 = *(const int4*)(Bp + 8);
    *(int4*)&As[sr][sh * 16]     = av0;
    *(int4*)&As[sr][sh * 16 + 8] = av1;
    *(int4*)&Bs[sr][sh * 16]     = bv0;
    *(int4*)&Bs[sr][sh * 16 + 8] = bv1;
    __syncthreads();
    f16x8 af[4], bfr[4];
#pragma unroll
    for (int i = 0; i < 4; i++) af[i] = *(const f16x8*)&As[wr * 64 + i * 16 + q16][8 * g];
#pragma unroll
    for (int j = 0; j < 4; j++) bfr[j] = *(const f16x8*)&Bs[wc * 64 + j * 16 + q16][8 * g];
#pragma unroll
    for (int i = 0; i < 4; i++)
#pragma unroll
      for (int j = 0; j < 4; j++)
        acc[i][j] = __builtin_amdgcn_mfma_f32_16x16x32_f16(af[i], bfr[j], acc[i][j], 0, 0, 0);
    __syncthreads();
  }

#pragma unroll
  for (int i = 0; i < 4; i++)
#pragma unroll
    for (int j = 0; j < 4; j++) {
      const int n = n0 + wc * 64 + j * 16 + q16;
      const float bs = bias[n];
      const int mbase = m0 + wr * 64 + i * 16 + 4 * g;
      if (MODE == 1) {
#pragma unroll
        for (int r = 0; r < 4; r++) Co[(size_t)(mbase + r) * N + n] = acc[i][j][r] + bs;
      } else {
        const int b = mbase >> 12, s = mbase & (S_LEN - 1);
        const int h = n / 192, rr = n - h * 192;
        const size_t bh = (size_t)b * NHEAD + h;
        if (rr < 64) {
#pragma unroll
          for (int r = 0; r < 4; r++)
            Qo[(bh * S_LEN + s + r) * HDIM + rr] = (f16)((acc[i][j][r] + bs) * 0.125f);
        } else if (rr < 128) {
#pragma unroll
          for (int r = 0; r < 4; r++)
            Ko[(bh * S_LEN + s + r) * HDIM + (rr - 64)] = (f16)(acc[i][j][r] + bs);
        } else {
#pragma unroll
          for (int r = 0; r < 4; r++)
            Vo[(bh * S_LEN + s + r) * HDIM + (rr - 128)] = (f16)(acc[i][j][r] + bs);  // V row-major
        }
      }
    }
}

// ---------------- sliding-window flash attention (LDS window) ----------------
// Q,K,V: [bh][s][64] f16 (Q pre-scaled by 1/8); out: [b][s][512] f16
// Block = 64 queries; stage 320-key K+V window in LDS (80 KB); 4 waves x 9 tiles pure-LDS.
// LDS map: Ks [0,40960): row r(0..319) pitch 128B, 16B slots XOR-swizzled by (r&7).
//          Vs [40960,81920): 128B block per (dt, 4-key group kg): byte(key',d) =
//            VSOFF + (d>>4)*10240 + (key'>>2)*128 + (key'&3)*32 + (d&15)*2
//          (4x16 row-major f16 matrix per block -> tr_b16 column reads)
#define VSOFF 40960

__global__ __launch_bounds__(256) void attn_kernel(
    const f16* __restrict__ Q, const f16* __restrict__ K,
    const f16* __restrict__ V, f16* __restrict__ O) {
  __shared__ __align__(16) char smem[81920];

  const int wg = blockIdx.x;
  const int vv = (wg & 7) * 128 + (wg >> 3);   // XCD swizzle (1024 % 8 == 0, bijective)
  const int bh = vv >> 6, qc = vv & 63;
  const int b = bh >> 3, h = bh & 7;
  const int tid = threadIdx.x;
  const int wid = tid >> 6, lane = tid & 63;
  const int g = lane >> 4, q16 = lane & 15;
  const int qb = qc * 64;          // block's first query
  const int wb = qb - 128;         // window base key (may be negative; staging clamps)
  const int qw = qb + wid * 16;    // this wave's 16 queries
  const int qg = qw + q16;

  const f16* Kb_g = K + (size_t)bh * S_LEN * HDIM;
  const f16* Vb_g = V + (size_t)bh * S_LEN * HDIM;

  // ---- stage K window: 320 rows x 64 dims, coalesced, XOR-swizzled 16B slots ----
#pragma unroll
  for (int rd = 0; rd < 10; ++rd) {
    const int idx = rd * 256 + tid;
    const int r = idx >> 3, sl = idx & 7;           // row, 16B slot (dims 8*sl..8*sl+7)
    const int key = min(max(wb + r, 0), S_LEN - 1); // clamped rows masked in compute
    int4 kvv = *(const int4*)(Kb_g + (size_t)key * HDIM + sl * 8);
    *(int4*)(smem + r * 128 + ((sl ^ (r & 7)) << 4)) = kvv;
  }
  // ---- stage V window into tr_b16-compatible subtiled layout ----
#pragma unroll
  for (int rd = 0; rd < 10; ++rd) {
    const int idx = rd * 256 + tid;
    const int r = idx >> 3, c8 = (idx & 7) * 8;     // key-row, dim start
    const int key = min(max(wb + r, 0), S_LEN - 1);
    int4 vvv = *(const int4*)(Vb_g + (size_t)key * HDIM + c8);
    *(int4*)(smem + VSOFF + (c8 >> 4) * 10240 + (r >> 2) * 128 + (r & 3) * 32 + ((c8 & 8) << 1)) = vvv;
  }
  __syncthreads();

  const f16* Qb = Q + ((size_t)bh * S_LEN + qw) * HDIM;
  f16x8 qf0 = *(const f16x8*)(Qb + q16 * HDIM + 8 * g);        // d 0..31
  f16x8 qf1 = *(const f16x8*)(Qb + q16 * HDIM + 32 + 8 * g);   // d 32..63

  f32x4 zero = {0.f, 0.f, 0.f, 0.f};
  f32x4 o[4];
#pragma unroll
  for (int dt = 0; dt < 4; dt++) o[dt] = zero;
  float m_run = 0.f;   // static base; vote-guarded rescale (round-4 scheme)
  float l_run = 0.f;

  // per-lane tr_b16 address term: lane (g,q16) reads COLUMN q16 of BLOCK (kc>>2)+g.
  // (m156/m162: the lane pattern comes from the per-lane ADDRESS — a uniform
  //  address makes every lane read the same value. Round-6 bug was exactly that.)
  const unsigned troff = (unsigned)(g * 128 + q16 * 8);

#pragma unroll
  for (int t = 0; t < 9; ++t) {
    const int kAp = wid * 16 + 32 * t;   // window coords of chunk A
    const int kBp = kAp + 16;            // chunk B (may be 320 for w=3,t=8: fully masked)
    // K fragments from swizzled LDS (rows kAp+q16 / kBp+q16; slots g, g+4)
    const int rrA = kAp + q16;
    const int rrB = kBp + q16;
    f16x8 ka0 = *(const f16x8*)(smem + rrA * 128 + (((g    ) ^ (rrA & 7)) << 4));
    f16x8 ka1 = *(const f16x8*)(smem + rrA * 128 + (((g + 4) ^ (rrA & 7)) << 4));
    f16x8 kb0 = *(const f16x8*)(smem + rrB * 128 + (((g    ) ^ (rrB & 7)) << 4));
    f16x8 kb1 = *(const f16x8*)(smem + rrB * 128 + (((g + 4) ^ (rrB & 7)) << 4));

    f32x4 sA = zero, sB = zero;
    sA = __builtin_amdgcn_mfma_f32_16x16x32_f16(ka0, qf0, sA, 0, 0, 0);
    sA = __builtin_amdgcn_mfma_f32_16x16x32_f16(ka1, qf1, sA, 0, 0, 0);
    sB = __builtin_amdgcn_mfma_f32_16x16x32_f16(kb0, qf0, sB, 0, 0, 0);
    sB = __builtin_amdgcn_mfma_f32_16x16x32_f16(kb1, qf1, sB, 0, 0, 0);

    // mask (window + range); lane-local max only
    float sv[8];
    float mx = -INFINITY;
#pragma unroll
    for (int i = 0; i < 4; i++) {
      const int kgA = wb + kAp + 4 * g + i;
      const int kgB = wb + kBp + 4 * g + i;
      const bool okA = ((unsigned)(kgA - qg + 128) <= 256u) && ((unsigned)kgA < S_LEN);
      const bool okB = ((unsigned)(kgB - qg + 128) <= 256u) && ((unsigned)kgB < S_LEN);
      sv[i]     = okA ? sA[i] : -INFINITY;
      sv[i + 4] = okB ? sB[i] : -INFINITY;
      mx = fmaxf(mx, fmaxf(sv[i], sv[i + 4]));
    }

    // speculative p = exp(sv - m_run); corrected on the (~never) cold path
    float pA[4], pB[4];
#pragma unroll
    for (int i = 0; i < 4; i++) {
      pA[i] = EXP2F((sv[i] - m_run) * LOG2E);
      pB[i] = EXP2F((sv[i + 4] - m_run) * LOG2E);
    }

    if (__builtin_expect(!__all(mx - m_run <= 8.f), 0)) {
      float mxq = fmaxf(mx, __shfl_xor(mx, 16));
      mxq = fmaxf(mxq, __shfl_xor(mxq, 32));
      const float mnew = fmaxf(m_run, mxq);
      const float resc = EXP2F((m_run - mnew) * LOG2E);   // per query q16
#pragma unroll
      for (int i = 0; i < 4; i++) { pA[i] *= resc; pB[i] *= resc; }
      l_run *= resc;
      float ri[4];
#pragma unroll
      for (int i = 0; i < 4; i++) ri[i] = __shfl(resc, 4 * g + i);
#pragma unroll
      for (int dt = 0; dt < 4; dt++)
#pragma unroll
        for (int i = 0; i < 4; i++) o[dt][i] *= ri[i];
      m_run = mnew;
    }

    f16x4 pfA, pfB;
#pragma unroll
    for (int i = 0; i < 4; i++) {
      l_run += pA[i] + pB[i];
      pfA[i] = (f16)pA[i];
      pfB[i] = (f16)pB[i];
    }

    // V B-fragments via LDS transpose-read: lane (g,q16) reads column q16 of
    // block (kc>>2)+g  ->  B[k=4g+j][n=q16] = V[kc+4g+j][dt*16+q16].
    const int kcA = kAp;
    const int kcB = min(kBp, 304);   // overflow tile is fully masked (pfB==0)
    f16x4 bA[4], bB[4];
#pragma unroll
    for (int dt = 0; dt < 4; ++dt) {
      unsigned aA = (unsigned)(uintptr_t)(smem + VSOFF + dt * 10240 + (kcA >> 2) * 128) + troff;
      unsigned aB = (unsigned)(uintptr_t)(smem + VSOFF + dt * 10240 + (kcB >> 2) * 128) + troff;
      asm volatile("ds_read_b64_tr_b16 %0, %1" : "=v"(bA[dt]) : "v"(aA));
      asm volatile("ds_read_b64_tr_b16 %0, %1" : "=v"(bB[dt]) : "v"(aB));
    }
    asm volatile("s_waitcnt lgkmcnt(0)" ::: "memory");
    __builtin_amdgcn_sched_barrier(0);

#pragma unroll
    for (int dt = 0; dt < 4; dt++) {
      o[dt] = __builtin_amdgcn_mfma_f32_16x16x16f16(pfA, bA[dt], o[dt], 0, 0, 0);
      o[dt] = __builtin_amdgcn_mfma_f32_16x16x16f16(pfB, bB[dt], o[dt], 0, 0, 0);
    }
  }

  // epilogue: reduce l across the 4 g-groups (same query), normalize, store
  l_run += __shfl_xor(l_run, 16);
  l_run += __shfl_xor(l_run, 32);
  const float linv = 1.f / l_run;
  float li[4];
#pragma unroll
  for (int i = 0; i < 4; i++) li[i] = __shfl(linv, 4 * g + i);
#pragma unroll
  for (int dt = 0; dt < 4; dt++)
#pragma unroll
    for (int i = 0; i < 4; i++) {
      const int s_idx = qw + 4 * g + i;
      O[((size_t)b * S_LEN + s_idx) * EMB + h * HDIM + dt * 16 + q16] = (f16)(o[dt][i] * li[i]);
    }
}

// ---------------- launch ----------------
extern "C" void kernel_launch(void* const* d_in, const int* in_sizes, int n_in,
                              void* d_out, int out_size, void* d_ws, size_t ws_size,
                              hipStream_t stream) {
  const float* x     = (const float*)d_in[0];
  const float* w_qkv = (const float*)d_in[1];
  const float* b_qkv = (const float*)d_in[2];
  const float* w_o   = (const float*)d_in[3];
  const float* b_o   = (const float*)d_in[4];
  float* out = (float*)d_out;

  char* ws = (char*)d_ws;
  f16* xb    = (f16*)(ws);                 // [8192][512]        8.0 MiB
  f16* wqkvt = (f16*)(ws + 8388608);       // [1536][512]        1.5 MiB
  f16* wot   = (f16*)(ws + 9961472);       // [512][512]         0.5 MiB
  f16* Qs    = (f16*)(ws + 10485760);      // [16][4096][64]     8 MiB
  f16* Ks    = (f16*)(ws + 18874368);      // [16][4096][64]     8 MiB
  f16* Vs    = (f16*)(ws + 27262976);      // [16][4096][64]     8 MiB (row-major)
  f16* attn  = (f16*)(ws + 35651584);      // [8192][512]        8 MiB

  cast_f32_f16_kernel<<<4096, 256, 0, stream>>>(x, xb, 8192 * 512);
  transpose_cast_kernel<<<3072, 256, 0, stream>>>(w_qkv, wqkvt, 512, 1536);
  transpose_cast_kernel<<<1024, 256, 0, stream>>>(w_o, wot, 512, 512);
  gemm_bt_kernel<0><<<dim3(64, 12), 256, 0, stream>>>(xb, wqkvt, b_qkv, Qs, Ks, Vs,
                                                      (float*)nullptr, 8192, 1536);
  attn_kernel<<<1024, 256, 0, stream>>>(Qs, Ks, Vs, attn);
  gemm_bt_kernel<1><<<dim3(64, 4), 256, 0, stream>>>(attn, wot, b_o,
                                                     (f16*)nullptr, (f16*)nullptr, (f16*)nullptr,
                                                     out, 8192, 512);
}

// Round 8
// 73.137 us; speedup vs baseline: 1.5353x; 1.0691x over previous
//
#include <hip/hip_runtime.h>
#include <hip/hip_bf16.h>
#include <math.h>

typedef _Float16 f16;
typedef __attribute__((ext_vector_type(8))) _Float16 f16x8;
typedef __attribute__((ext_vector_type(4))) _Float16 f16x4;
typedef __attribute__((ext_vector_type(4))) float f32x4;

#define S_LEN 4096
#define NHEAD 8
#define HDIM 64
#define EMB 512
#define KDIM 512
#define LOG2E 1.4426950408889634f

#if __has_builtin(__builtin_amdgcn_exp2f)
#define EXP2F(x) __builtin_amdgcn_exp2f(x)
#else
#define EXP2F(x) exp2f(x)
#endif

// direct HBM->LDS 16B copy: lds dest = wave-uniform base + lane*16 (linear),
// global src is per-lane. CK-style addrspace casts (flat->AS3 = low-32 trunc).
__device__ __forceinline__ void g2l16(const void* g, void* l) {
  __builtin_amdgcn_global_load_lds(
      reinterpret_cast<const __attribute__((address_space(1))) unsigned int*>(
          reinterpret_cast<uintptr_t>(g)),
      reinterpret_cast<__attribute__((address_space(3))) unsigned int*>(
          static_cast<unsigned int>(reinterpret_cast<uintptr_t>(l))),
      16, 0, 0);
}

// ---------------- cast / transpose ----------------
__global__ void cast_f32_f16_kernel(const float* __restrict__ in, f16* __restrict__ out, int n) {
  int i = (blockIdx.x * 256 + threadIdx.x) * 4;
  if (i >= n) return;
  float4 v = *(const float4*)(in + i);
  f16x4 o = { (f16)v.x, (f16)v.y, (f16)v.z, (f16)v.w };
  *(f16x4*)(out + i) = o;
}

// in [R][C] f32  ->  out [C][R] f16
__global__ void transpose_cast_kernel(const float* __restrict__ in, f16* __restrict__ out, int R, int C) {
  int idx = blockIdx.x * 256 + threadIdx.x;
  if (idx >= R * C) return;
  int r = idx / C, c = idx - r * C;
  out[(size_t)c * R + r] = (f16)in[idx];
}

// ---------------- GEMM: C[M][N] = A[M][K] * Bt[N][K]^T + bias ----------------
// m97-style staging: global_load_lds dwordx4 into LINEAR LDS tiles, 2-barrier loop.
#define TM 128
#define TN 128
#define TK 32

template<int MODE>
__global__ __launch_bounds__(256) void gemm_bt_kernel(
    const f16* __restrict__ A, const f16* __restrict__ Bt, const float* __restrict__ bias,
    f16* __restrict__ Qo, f16* __restrict__ Ko, f16* __restrict__ Vo,
    float* __restrict__ Co, int M, int N) {
  __shared__ f16 As[TM][TK];   // linear (no pad): gload_lds needs dest contiguous in lane order
  __shared__ f16 Bs[TN][TK];
  const int m0 = blockIdx.x * TM, n0 = blockIdx.y * TN;
  const int tid = threadIdx.x;
  const int lane = tid & 63, wid = tid >> 6;
  const int wr = wid >> 1, wc = wid & 1;      // 2x2 wave grid, each wave 64x64
  const int g = lane >> 4, q16 = lane & 15;

  // staging geometry: chunk = 16 rows = 1024 B; wave w stages chunks {2w, 2w+1} of A and B.
  // lane l -> row l>>2 within chunk, 16B slot l&3  (matches LDS byte = lane*16).
  const int srow = lane >> 2;
  const int skof = (lane & 3) * 8;
  const int c0 = wid * 2, c1 = wid * 2 + 1;
  const f16* A0 = A  + (size_t)(m0 + c0 * 16 + srow) * KDIM + skof;
  const f16* A1 = A  + (size_t)(m0 + c1 * 16 + srow) * KDIM + skof;
  const f16* B0 = Bt + (size_t)(n0 + c0 * 16 + srow) * KDIM + skof;
  const f16* B1 = Bt + (size_t)(n0 + c1 * 16 + srow) * KDIM + skof;
  char* lA0 = (char*)As + c0 * 1024;
  char* lA1 = (char*)As + c1 * 1024;
  char* lB0 = (char*)Bs + c0 * 1024;
  char* lB1 = (char*)Bs + c1 * 1024;

  f32x4 zero = {0.f, 0.f, 0.f, 0.f};
  f32x4 acc[4][4];
#pragma unroll
  for (int i = 0; i < 4; i++)
#pragma unroll
    for (int j = 0; j < 4; j++) acc[i][j] = zero;

  for (int kk = 0; kk < KDIM; kk += TK) {
    g2l16(A0 + kk, lA0);
    g2l16(A1 + kk, lA1);
    g2l16(B0 + kk, lB0);
    g2l16(B1 + kk, lB1);
    __syncthreads();   // drains vmcnt (gload_lds) + joins waves
    f16x8 af[4], bfr[4];
#pragma unroll
    for (int i = 0; i < 4; i++) af[i] = *(const f16x8*)&As[wr * 64 + i * 16 + q16][8 * g];
#pragma unroll
    for (int j = 0; j < 4; j++) bfr[j] = *(const f16x8*)&Bs[wc * 64 + j * 16 + q16][8 * g];
#pragma unroll
    for (int i = 0; i < 4; i++)
#pragma unroll
      for (int j = 0; j < 4; j++)
        acc[i][j] = __builtin_amdgcn_mfma_f32_16x16x32_f16(af[i], bfr[j], acc[i][j], 0, 0, 0);
    __syncthreads();   // all ds_reads done before next-iter staging overwrites
  }

#pragma unroll
  for (int i = 0; i < 4; i++)
#pragma unroll
    for (int j = 0; j < 4; j++) {
      const int n = n0 + wc * 64 + j * 16 + q16;
      const float bs = bias[n];
      const int mbase = m0 + wr * 64 + i * 16 + 4 * g;
      if (MODE == 1) {
#pragma unroll
        for (int r = 0; r < 4; r++) Co[(size_t)(mbase + r) * N + n] = acc[i][j][r] + bs;
      } else {
        const int b = mbase >> 12, s = mbase & (S_LEN - 1);
        const int h = n / 192, rr = n - h * 192;
        const size_t bh = (size_t)b * NHEAD + h;
        if (rr < 64) {
#pragma unroll
          for (int r = 0; r < 4; r++)
            Qo[(bh * S_LEN + s + r) * HDIM + rr] = (f16)((acc[i][j][r] + bs) * 0.125f);
        } else if (rr < 128) {
#pragma unroll
          for (int r = 0; r < 4; r++)
            Ko[(bh * S_LEN + s + r) * HDIM + (rr - 64)] = (f16)(acc[i][j][r] + bs);
        } else {
#pragma unroll
          for (int r = 0; r < 4; r++)
            Vo[(bh * S_LEN + s + r) * HDIM + (rr - 128)] = (f16)(acc[i][j][r] + bs);  // V row-major
        }
      }
    }
}

// ---------------- sliding-window flash attention (LDS window) ----------------
// Q,K,V: [bh][s][64] f16 (Q pre-scaled by 1/8); out: [b][s][512] f16
// Block = 64 queries; stage 320-key K+V window in LDS (80 KB); 4 waves x 9 tiles pure-LDS.
// LDS map: Ks [0,40960): row r(0..319) pitch 128B, 16B slots XOR-swizzled by (r&7).
//          Vs [40960,81920): 128B block per (dt, 4-key group kg): byte(key',d) =
//            VSOFF + (d>>4)*10240 + (key'>>2)*128 + (key'&3)*32 + (d&15)*2
//          (4x16 row-major f16 matrix per block -> tr_b16 column reads)
#define VSOFF 40960

__global__ __launch_bounds__(256) void attn_kernel(
    const f16* __restrict__ Q, const f16* __restrict__ K,
    const f16* __restrict__ V, f16* __restrict__ O) {
  __shared__ __align__(16) char smem[81920];

  const int wg = blockIdx.x;
  const int vv = (wg & 7) * 128 + (wg >> 3);   // XCD swizzle (1024 % 8 == 0, bijective)
  const int bh = vv >> 6, qc = vv & 63;
  const int b = bh >> 3, h = bh & 7;
  const int tid = threadIdx.x;
  const int wid = tid >> 6, lane = tid & 63;
  const int g = lane >> 4, q16 = lane & 15;
  const int qb = qc * 64;          // block's first query
  const int wb = qb - 128;         // window base key (may be negative; staging clamps)
  const int qw = qb + wid * 16;    // this wave's 16 queries
  const int qg = qw + q16;

  const f16* Kb_g = K + (size_t)bh * S_LEN * HDIM;
  const f16* Vb_g = V + (size_t)bh * S_LEN * HDIM;

  // ---- stage K window: 320 rows x 64 dims, coalesced, XOR-swizzled 16B slots ----
#pragma unroll
  for (int rd = 0; rd < 10; ++rd) {
    const int idx = rd * 256 + tid;
    const int r = idx >> 3, sl = idx & 7;           // row, 16B slot (dims 8*sl..8*sl+7)
    const int key = min(max(wb + r, 0), S_LEN - 1); // clamped rows masked in compute
    int4 kvv = *(const int4*)(Kb_g + (size_t)key * HDIM + sl * 8);
    *(int4*)(smem + r * 128 + ((sl ^ (r & 7)) << 4)) = kvv;
  }
  // ---- stage V window into tr_b16-compatible subtiled layout ----
#pragma unroll
  for (int rd = 0; rd < 10; ++rd) {
    const int idx = rd * 256 + tid;
    const int r = idx >> 3, c8 = (idx & 7) * 8;     // key-row, dim start
    const int key = min(max(wb + r, 0), S_LEN - 1);
    int4 vvv = *(const int4*)(Vb_g + (size_t)key * HDIM + c8);
    *(int4*)(smem + VSOFF + (c8 >> 4) * 10240 + (r >> 2) * 128 + (r & 3) * 32 + ((c8 & 8) << 1)) = vvv;
  }
  __syncthreads();

  const f16* Qb = Q + ((size_t)bh * S_LEN + qw) * HDIM;
  f16x8 qf0 = *(const f16x8*)(Qb + q16 * HDIM + 8 * g);        // d 0..31
  f16x8 qf1 = *(const f16x8*)(Qb + q16 * HDIM + 32 + 8 * g);   // d 32..63

  f32x4 zero = {0.f, 0.f, 0.f, 0.f};
  f32x4 o[4];
#pragma unroll
  for (int dt = 0; dt < 4; dt++) o[dt] = zero;
  float m_run = 0.f;   // static base; vote-guarded rescale (round-4 scheme)
  float l_run = 0.f;

  // per-lane tr_b16 address term: lane (g,q16) reads COLUMN q16 of BLOCK (kc>>2)+g.
  const unsigned troff = (unsigned)(g * 128 + q16 * 8);

#pragma unroll
  for (int t = 0; t < 9; ++t) {
    const int kAp = wid * 16 + 32 * t;   // window coords of chunk A
    const int kBp = kAp + 16;            // chunk B (may be 320 for w=3,t=8: fully masked)
    // K fragments from swizzled LDS (rows kAp+q16 / kBp+q16; slots g, g+4)
    const int rrA = kAp + q16;
    const int rrB = kBp + q16;
    f16x8 ka0 = *(const f16x8*)(smem + rrA * 128 + (((g    ) ^ (rrA & 7)) << 4));
    f16x8 ka1 = *(const f16x8*)(smem + rrA * 128 + (((g + 4) ^ (rrA & 7)) << 4));
    f16x8 kb0 = *(const f16x8*)(smem + rrB * 128 + (((g    ) ^ (rrB & 7)) << 4));
    f16x8 kb1 = *(const f16x8*)(smem + rrB * 128 + (((g + 4) ^ (rrB & 7)) << 4));

    f32x4 sA = zero, sB = zero;
    sA = __builtin_amdgcn_mfma_f32_16x16x32_f16(ka0, qf0, sA, 0, 0, 0);
    sA = __builtin_amdgcn_mfma_f32_16x16x32_f16(ka1, qf1, sA, 0, 0, 0);
    sB = __builtin_amdgcn_mfma_f32_16x16x32_f16(kb0, qf0, sB, 0, 0, 0);
    sB = __builtin_amdgcn_mfma_f32_16x16x32_f16(kb1, qf1, sB, 0, 0, 0);

    // mask (window + range); lane-local max only
    float sv[8];
    float mx = -INFINITY;
#pragma unroll
    for (int i = 0; i < 4; i++) {
      const int kgA = wb + kAp + 4 * g + i;
      const int kgB = wb + kBp + 4 * g + i;
      const bool okA = ((unsigned)(kgA - qg + 128) <= 256u) && ((unsigned)kgA < S_LEN);
      const bool okB = ((unsigned)(kgB - qg + 128) <= 256u) && ((unsigned)kgB < S_LEN);
      sv[i]     = okA ? sA[i] : -INFINITY;
      sv[i + 4] = okB ? sB[i] : -INFINITY;
      mx = fmaxf(mx, fmaxf(sv[i], sv[i + 4]));
    }

    // speculative p = exp(sv - m_run); corrected on the (~never) cold path
    float pA[4], pB[4];
#pragma unroll
    for (int i = 0; i < 4; i++) {
      pA[i] = EXP2F((sv[i] - m_run) * LOG2E);
      pB[i] = EXP2F((sv[i + 4] - m_run) * LOG2E);
    }

    if (__builtin_expect(!__all(mx - m_run <= 8.f), 0)) {
      float mxq = fmaxf(mx, __shfl_xor(mx, 16));
      mxq = fmaxf(mxq, __shfl_xor(mxq, 32));
      const float mnew = fmaxf(m_run, mxq);
      const float resc = EXP2F((m_run - mnew) * LOG2E);   // per query q16
#pragma unroll
      for (int i = 0; i < 4; i++) { pA[i] *= resc; pB[i] *= resc; }
      l_run *= resc;
      float ri[4];
#pragma unroll
      for (int i = 0; i < 4; i++) ri[i] = __shfl(resc, 4 * g + i);
#pragma unroll
      for (int dt = 0; dt < 4; dt++)
#pragma unroll
        for (int i = 0; i < 4; i++) o[dt][i] *= ri[i];
      m_run = mnew;
    }

    f16x4 pfA, pfB;
#pragma unroll
    for (int i = 0; i < 4; i++) {
      l_run += pA[i] + pB[i];
      pfA[i] = (f16)pA[i];
      pfB[i] = (f16)pB[i];
    }

    // V B-fragments via LDS transpose-read: lane (g,q16) reads column q16 of
    // block (kc>>2)+g  ->  B[k=4g+j][n=q16] = V[kc+4g+j][dt*16+q16].
    const int kcA = kAp;
    const int kcB = min(kBp, 304);   // overflow tile is fully masked (pfB==0)
    f16x4 bA[4], bB[4];
#pragma unroll
    for (int dt = 0; dt < 4; ++dt) {
      unsigned aA = (unsigned)(uintptr_t)(smem + VSOFF + dt * 10240 + (kcA >> 2) * 128) + troff;
      unsigned aB = (unsigned)(uintptr_t)(smem + VSOFF + dt * 10240 + (kcB >> 2) * 128) + troff;
      asm volatile("ds_read_b64_tr_b16 %0, %1" : "=v"(bA[dt]) : "v"(aA));
      asm volatile("ds_read_b64_tr_b16 %0, %1" : "=v"(bB[dt]) : "v"(aB));
    }
    asm volatile("s_waitcnt lgkmcnt(0)" ::: "memory");
    __builtin_amdgcn_sched_barrier(0);

#pragma unroll
    for (int dt = 0; dt < 4; dt++) {
      o[dt] = __builtin_amdgcn_mfma_f32_16x16x16f16(pfA, bA[dt], o[dt], 0, 0, 0);
      o[dt] = __builtin_amdgcn_mfma_f32_16x16x16f16(pfB, bB[dt], o[dt], 0, 0, 0);
    }
  }

  // epilogue: reduce l across the 4 g-groups (same query), normalize, store
  l_run += __shfl_xor(l_run, 16);
  l_run += __shfl_xor(l_run, 32);
  const float linv = 1.f / l_run;
  float li[4];
#pragma unroll
  for (int i = 0; i < 4; i++) li[i] = __shfl(linv, 4 * g + i);
#pragma unroll
  for (int dt = 0; dt < 4; dt++)
#pragma unroll
    for (int i = 0; i < 4; i++) {
      const int s_idx = qw + 4 * g + i;
      O[((size_t)b * S_LEN + s_idx) * EMB + h * HDIM + dt * 16 + q16] = (f16)(o[dt][i] * li[i]);
    }
}

// ---------------- launch ----------------
extern "C" void kernel_launch(void* const* d_in, const int* in_sizes, int n_in,
                              void* d_out, int out_size, void* d_ws, size_t ws_size,
                              hipStream_t stream) {
  const float* x     = (const float*)d_in[0];
  const float* w_qkv = (const float*)d_in[1];
  const float* b_qkv = (const float*)d_in[2];
  const float* w_o   = (const float*)d_in[3];
  const float* b_o   = (const float*)d_in[4];
  float* out = (float*)d_out;

  char* ws = (char*)d_ws;
  f16* xb    = (f16*)(ws);                 // [8192][512]        8.0 MiB
  f16* wqkvt = (f16*)(ws + 8388608);       // [1536][512]        1.5 MiB
  f16* wot   = (f16*)(ws + 9961472);       // [512][512]         0.5 MiB
  f16* Qs    = (f16*)(ws + 10485760);      // [16][4096][64]     8 MiB
  f16* Ks    = (f16*)(ws + 18874368);      // [16][4096][64]     8 MiB
  f16* Vs    = (f16*)(ws + 27262976);      // [16][4096][64]     8 MiB (row-major)
  f16* attn  = (f16*)(ws + 35651584);      // [8192][512]        8 MiB

  cast_f32_f16_kernel<<<4096, 256, 0, stream>>>(x, xb, 8192 * 512);
  transpose_cast_kernel<<<3072, 256, 0, stream>>>(w_qkv, wqkvt, 512, 1536);
  transpose_cast_kernel<<<1024, 256, 0, stream>>>(w_o, wot, 512, 512);
  gemm_bt_kernel<0><<<dim3(64, 12), 256, 0, stream>>>(xb, wqkvt, b_qkv, Qs, Ks, Vs,
                                                      (float*)nullptr, 8192, 1536);
  attn_kernel<<<1024, 256, 0, stream>>>(Qs, Ks, Vs, attn);
  gemm_bt_kernel<1><<<dim3(64, 4), 256, 0, stream>>>(attn, wot, b_o,
                                                     (f16*)nullptr, (f16*)nullptr, (f16*)nullptr,
                                                     out, 8192, 512);
}

// Round 9
// 67.410 us; speedup vs baseline: 1.6657x; 1.0850x over previous
//
#include <hip/hip_runtime.h>
#include <hip/hip_bf16.h>
#include <math.h>

typedef _Float16 f16;
typedef __attribute__((ext_vector_type(8))) _Float16 f16x8;
typedef __attribute__((ext_vector_type(4))) _Float16 f16x4;
typedef __attribute__((ext_vector_type(4))) float f32x4;

#define S_LEN 4096
#define NHEAD 8
#define HDIM 64
#define EMB 512
#define KDIM 512
#define LOG2E 1.4426950408889634f

#if __has_builtin(__builtin_amdgcn_exp2f)
#define EXP2F(x) __builtin_amdgcn_exp2f(x)
#else
#define EXP2F(x) exp2f(x)
#endif

// direct HBM->LDS 16B copy: lds dest = wave-uniform base (+ lane*16 by HW),
// global src is per-lane. CK-style addrspace casts (flat->AS3 = low-32 trunc).
__device__ __forceinline__ void g2l16(const void* g, void* l) {
  __builtin_amdgcn_global_load_lds(
      reinterpret_cast<const __attribute__((address_space(1))) unsigned int*>(
          reinterpret_cast<uintptr_t>(g)),
      reinterpret_cast<__attribute__((address_space(3))) unsigned int*>(
          static_cast<unsigned int>(reinterpret_cast<uintptr_t>(l))),
      16, 0, 0);
}

// ---------------- cast / transpose ----------------
__global__ void cast_f32_f16_kernel(const float* __restrict__ in, f16* __restrict__ out, int n) {
  int i = (blockIdx.x * 256 + threadIdx.x) * 4;
  if (i >= n) return;
  float4 v = *(const float4*)(in + i);
  f16x4 o = { (f16)v.x, (f16)v.y, (f16)v.z, (f16)v.w };
  *(f16x4*)(out + i) = o;
}

// in [R][C] f32 -> out [C][R] f16, LDS-tiled 64x64 so both streams are coalesced.
// R, C multiples of 64 (512/1536/512 here).
__global__ void transpose_cast_kernel(const float* __restrict__ in, f16* __restrict__ out, int R, int C) {
  __shared__ f16 tile[64][65];  // +1 pad: column reads conflict-free
  const int c0 = blockIdx.x * 64, r0 = blockIdx.y * 64;
  const int tid = threadIdx.x;
#pragma unroll
  for (int i = 0; i < 16; ++i) {
    const int idx = i * 256 + tid;
    const int lr = idx >> 6, lc = idx & 63;
    tile[lr][lc] = (f16)in[(size_t)(r0 + lr) * C + (c0 + lc)];  // coalesced read
  }
  __syncthreads();
#pragma unroll
  for (int i = 0; i < 16; ++i) {
    const int idx = i * 256 + tid;
    const int lc = idx >> 6, lr = idx & 63;
    out[(size_t)(c0 + lc) * R + (r0 + lr)] = tile[lr][lc];      // coalesced write
  }
}

// ---------------- GEMM: C[M][N] = A[M][K] * Bt[N][K]^T + bias ----------------
// m97-style staging: global_load_lds dwordx4 into LINEAR LDS tiles, 2-barrier loop.
// TM fixed 128 (4 waves, 2x2 wave grid: rows wr*64, cols wc*(TN/2)).
#define TM 128
#define TK 32

template<int MODE, int TN>
__global__ __launch_bounds__(256) void gemm_bt_kernel(
    const f16* __restrict__ A, const f16* __restrict__ Bt, const float* __restrict__ bias,
    f16* __restrict__ Qo, f16* __restrict__ Ko, f16* __restrict__ Vo,
    float* __restrict__ Co, int M, int N) {
  constexpr int JN = TN / 32;    // B-frags / acc cols per wave (4 for TN=128, 2 for TN=64)
  constexpr int BCH = TN / 64;   // B staging chunks per wave (2 or 1)
  __shared__ f16 As[TM][TK];     // linear: gload_lds dest contiguous in lane order
  __shared__ f16 Bs[TN][TK];
  const int m0 = blockIdx.x * TM, n0 = blockIdx.y * TN;
  const int tid = threadIdx.x;
  const int lane = tid & 63, wid = tid >> 6;
  const int wr = wid >> 1, wc = wid & 1;
  const int g = lane >> 4, q16 = lane & 15;

  // staging geometry: chunk = 16 rows = 1024 B; lane l -> row l>>2, 16B slot l&3.
  const int srow = lane >> 2;
  const int skof = (lane & 3) * 8;
  const f16* Ag[2]; char* Al[2];
#pragma unroll
  for (int cb = 0; cb < 2; ++cb) {
    const int ch = wid * 2 + cb;
    Ag[cb] = A + (size_t)(m0 + ch * 16 + srow) * KDIM + skof;
    Al[cb] = (char*)As + ch * 1024;
  }
  const f16* Bg[BCH]; char* Bl[BCH];
#pragma unroll
  for (int cb = 0; cb < BCH; ++cb) {
    const int ch = wid * BCH + cb;
    Bg[cb] = Bt + (size_t)(n0 + ch * 16 + srow) * KDIM + skof;
    Bl[cb] = (char*)Bs + ch * 1024;
  }

  f32x4 zero = {0.f, 0.f, 0.f, 0.f};
  f32x4 acc[4][JN];
#pragma unroll
  for (int i = 0; i < 4; i++)
#pragma unroll
    for (int j = 0; j < JN; j++) acc[i][j] = zero;

  for (int kk = 0; kk < KDIM; kk += TK) {
    g2l16(Ag[0] + kk, Al[0]);
    g2l16(Ag[1] + kk, Al[1]);
#pragma unroll
    for (int cb = 0; cb < BCH; ++cb) g2l16(Bg[cb] + kk, Bl[cb]);
    __syncthreads();   // drains vmcnt (gload_lds) + joins waves
    f16x8 af[4], bfr[JN];
#pragma unroll
    for (int i = 0; i < 4; i++) af[i] = *(const f16x8*)&As[wr * 64 + i * 16 + q16][8 * g];
#pragma unroll
    for (int j = 0; j < JN; j++) bfr[j] = *(const f16x8*)&Bs[wc * (TN / 2) + j * 16 + q16][8 * g];
#pragma unroll
    for (int i = 0; i < 4; i++)
#pragma unroll
      for (int j = 0; j < JN; j++)
        acc[i][j] = __builtin_amdgcn_mfma_f32_16x16x32_f16(af[i], bfr[j], acc[i][j], 0, 0, 0);
    __syncthreads();   // all ds_reads done before next-iter staging overwrites
  }

#pragma unroll
  for (int i = 0; i < 4; i++)
#pragma unroll
    for (int j = 0; j < JN; j++) {
      const int n = n0 + wc * (TN / 2) + j * 16 + q16;
      const float bs = bias[n];
      const int mbase = m0 + wr * 64 + i * 16 + 4 * g;
      if (MODE == 1) {
#pragma unroll
        for (int r = 0; r < 4; r++) Co[(size_t)(mbase + r) * N + n] = acc[i][j][r] + bs;
      } else {
        const int b = mbase >> 12, s = mbase & (S_LEN - 1);
        const int h = n / 192, rr = n - h * 192;
        const size_t bh = (size_t)b * NHEAD + h;
        if (rr < 64) {
#pragma unroll
          for (int r = 0; r < 4; r++)
            Qo[(bh * S_LEN + s + r) * HDIM + rr] = (f16)((acc[i][j][r] + bs) * 0.125f);
        } else if (rr < 128) {
#pragma unroll
          for (int r = 0; r < 4; r++)
            Ko[(bh * S_LEN + s + r) * HDIM + (rr - 64)] = (f16)(acc[i][j][r] + bs);
        } else {
#pragma unroll
          for (int r = 0; r < 4; r++)
            Vo[(bh * S_LEN + s + r) * HDIM + (rr - 128)] = (f16)(acc[i][j][r] + bs);  // V row-major
        }
      }
    }
}

// ---------------- sliding-window flash attention (LDS window) ----------------
// Q,K,V: [bh][s][64] f16 (Q pre-scaled by 1/8); out: [b][s][512] f16
// Block = 64 queries; stage 320-key K+V window in LDS (80 KB); 4 waves x 9 tiles pure-LDS.
// LDS map: Ks [0,40960): row r(0..319) pitch 128B, 16B slots XOR-swizzled by (r&7).
//          Vs [40960,81920): 128B block per (dt, 4-key group kg): byte(key',d) =
//            VSOFF + (d>>4)*10240 + (key'>>2)*128 + (key'&3)*32 + (d&15)*2
//          (4x16 row-major f16 matrix per block -> tr_b16 column reads)
#define VSOFF 40960

__global__ __launch_bounds__(256) void attn_kernel(
    const f16* __restrict__ Q, const f16* __restrict__ K,
    const f16* __restrict__ V, f16* __restrict__ O) {
  __shared__ __align__(16) char smem[81920];

  const int wg = blockIdx.x;
  const int vv = (wg & 7) * 128 + (wg >> 3);   // XCD swizzle (1024 % 8 == 0, bijective)
  const int bh = vv >> 6, qc = vv & 63;
  const int b = bh >> 3, h = bh & 7;
  const int tid = threadIdx.x;
  const int wid = tid >> 6, lane = tid & 63;
  const int g = lane >> 4, q16 = lane & 15;
  const int qb = qc * 64;          // block's first query
  const int wb = qb - 128;         // window base key (may be negative; staging clamps)
  const int qw = qb + wid * 16;    // this wave's 16 queries
  const int qg = qw + q16;

  const f16* Kb_g = K + (size_t)bh * S_LEN * HDIM;
  const f16* Vb_g = V + (size_t)bh * S_LEN * HDIM;

  // ---- stage K window: 320 rows x 64 dims, coalesced, XOR-swizzled 16B slots ----
#pragma unroll
  for (int rd = 0; rd < 10; ++rd) {
    const int idx = rd * 256 + tid;
    const int r = idx >> 3, sl = idx & 7;           // row, 16B slot (dims 8*sl..8*sl+7)
    const int key = min(max(wb + r, 0), S_LEN - 1); // clamped rows masked in compute
    int4 kvv = *(const int4*)(Kb_g + (size_t)key * HDIM + sl * 8);
    *(int4*)(smem + r * 128 + ((sl ^ (r & 7)) << 4)) = kvv;
  }
  // ---- stage V window into tr_b16-compatible subtiled layout ----
#pragma unroll
  for (int rd = 0; rd < 10; ++rd) {
    const int idx = rd * 256 + tid;
    const int r = idx >> 3, c8 = (idx & 7) * 8;     // key-row, dim start
    const int key = min(max(wb + r, 0), S_LEN - 1);
    int4 vvv = *(const int4*)(Vb_g + (size_t)key * HDIM + c8);
    *(int4*)(smem + VSOFF + (c8 >> 4) * 10240 + (r >> 2) * 128 + (r & 3) * 32 + ((c8 & 8) << 1)) = vvv;
  }
  __syncthreads();

  const f16* Qb = Q + ((size_t)bh * S_LEN + qw) * HDIM;
  f16x8 qf0 = *(const f16x8*)(Qb + q16 * HDIM + 8 * g);        // d 0..31
  f16x8 qf1 = *(const f16x8*)(Qb + q16 * HDIM + 32 + 8 * g);   // d 32..63

  f32x4 zero = {0.f, 0.f, 0.f, 0.f};
  f32x4 o[4];
#pragma unroll
  for (int dt = 0; dt < 4; dt++) o[dt] = zero;
  float m_run = 0.f;   // static base; vote-guarded rescale (round-4 scheme)
  float l_run = 0.f;

  // per-lane tr_b16 address term: lane (g,q16) reads COLUMN q16 of BLOCK (kc>>2)+g.
  const unsigned troff = (unsigned)(g * 128 + q16 * 8);

#pragma unroll
  for (int t = 0; t < 9; ++t) {
    const int kAp = wid * 16 + 32 * t;   // window coords of chunk A
    const int kBp = kAp + 16;            // chunk B (may be 320 for w=3,t=8: fully masked)
    // K fragments from swizzled LDS (rows kAp+q16 / kBp+q16; slots g, g+4)
    const int rrA = kAp + q16;
    const int rrB = kBp + q16;
    f16x8 ka0 = *(const f16x8*)(smem + rrA * 128 + (((g    ) ^ (rrA & 7)) << 4));
    f16x8 ka1 = *(const f16x8*)(smem + rrA * 128 + (((g + 4) ^ (rrA & 7)) << 4));
    f16x8 kb0 = *(const f16x8*)(smem + rrB * 128 + (((g    ) ^ (rrB & 7)) << 4));
    f16x8 kb1 = *(const f16x8*)(smem + rrB * 128 + (((g + 4) ^ (rrB & 7)) << 4));

    f32x4 sA = zero, sB = zero;
    sA = __builtin_amdgcn_mfma_f32_16x16x32_f16(ka0, qf0, sA, 0, 0, 0);
    sA = __builtin_amdgcn_mfma_f32_16x16x32_f16(ka1, qf1, sA, 0, 0, 0);
    sB = __builtin_amdgcn_mfma_f32_16x16x32_f16(kb0, qf0, sB, 0, 0, 0);
    sB = __builtin_amdgcn_mfma_f32_16x16x32_f16(kb1, qf1, sB, 0, 0, 0);

    // mask (window + range); lane-local max only
    float sv[8];
    float mx = -INFINITY;
#pragma unroll
    for (int i = 0; i < 4; i++) {
      const int kgA = wb + kAp + 4 * g + i;
      const int kgB = wb + kBp + 4 * g + i;
      const bool okA = ((unsigned)(kgA - qg + 128) <= 256u) && ((unsigned)kgA < S_LEN);
      const bool okB = ((unsigned)(kgB - qg + 128) <= 256u) && ((unsigned)kgB < S_LEN);
      sv[i]     = okA ? sA[i] : -INFINITY;
      sv[i + 4] = okB ? sB[i] : -INFINITY;
      mx = fmaxf(mx, fmaxf(sv[i], sv[i + 4]));
    }

    // speculative p = exp(sv - m_run); corrected on the (~never) cold path
    float pA[4], pB[4];
#pragma unroll
    for (int i = 0; i < 4; i++) {
      pA[i] = EXP2F((sv[i] - m_run) * LOG2E);
      pB[i] = EXP2F((sv[i + 4] - m_run) * LOG2E);
    }

    if (__builtin_expect(!__all(mx - m_run <= 8.f), 0)) {
      float mxq = fmaxf(mx, __shfl_xor(mx, 16));
      mxq = fmaxf(mxq, __shfl_xor(mxq, 32));
      const float mnew = fmaxf(m_run, mxq);
      const float resc = EXP2F((m_run - mnew) * LOG2E);   // per query q16
#pragma unroll
      for (int i = 0; i < 4; i++) { pA[i] *= resc; pB[i] *= resc; }
      l_run *= resc;
      float ri[4];
#pragma unroll
      for (int i = 0; i < 4; i++) ri[i] = __shfl(resc, 4 * g + i);
#pragma unroll
      for (int dt = 0; dt < 4; dt++)
#pragma unroll
        for (int i = 0; i < 4; i++) o[dt][i] *= ri[i];
      m_run = mnew;
    }

    f16x4 pfA, pfB;
#pragma unroll
    for (int i = 0; i < 4; i++) {
      l_run += pA[i] + pB[i];
      pfA[i] = (f16)pA[i];
      pfB[i] = (f16)pB[i];
    }

    // V B-fragments via LDS transpose-read: lane (g,q16) reads column q16 of
    // block (kc>>2)+g  ->  B[k=4g+j][n=q16] = V[kc+4g+j][dt*16+q16].
    const int kcA = kAp;
    const int kcB = min(kBp, 304);   // overflow tile is fully masked (pfB==0)
    f16x4 bA[4], bB[4];
#pragma unroll
    for (int dt = 0; dt < 4; ++dt) {
      unsigned aA = (unsigned)(uintptr_t)(smem + VSOFF + dt * 10240 + (kcA >> 2) * 128) + troff;
      unsigned aB = (unsigned)(uintptr_t)(smem + VSOFF + dt * 10240 + (kcB >> 2) * 128) + troff;
      asm volatile("ds_read_b64_tr_b16 %0, %1" : "=v"(bA[dt]) : "v"(aA));
      asm volatile("ds_read_b64_tr_b16 %0, %1" : "=v"(bB[dt]) : "v"(aB));
    }
    asm volatile("s_waitcnt lgkmcnt(0)" ::: "memory");
    __builtin_amdgcn_sched_barrier(0);

#pragma unroll
    for (int dt = 0; dt < 4; dt++) {
      o[dt] = __builtin_amdgcn_mfma_f32_16x16x16f16(pfA, bA[dt], o[dt], 0, 0, 0);
      o[dt] = __builtin_amdgcn_mfma_f32_16x16x16f16(pfB, bB[dt], o[dt], 0, 0, 0);
    }
  }

  // epilogue: reduce l across the 4 g-groups (same query), normalize, store
  l_run += __shfl_xor(l_run, 16);
  l_run += __shfl_xor(l_run, 32);
  const float linv = 1.f / l_run;
  float li[4];
#pragma unroll
  for (int i = 0; i < 4; i++) li[i] = __shfl(linv, 4 * g + i);
#pragma unroll
  for (int dt = 0; dt < 4; dt++)
#pragma unroll
    for (int i = 0; i < 4; i++) {
      const int s_idx = qw + 4 * g + i;
      O[((size_t)b * S_LEN + s_idx) * EMB + h * HDIM + dt * 16 + q16] = (f16)(o[dt][i] * li[i]);
    }
}

// ---------------- launch ----------------
extern "C" void kernel_launch(void* const* d_in, const int* in_sizes, int n_in,
                              void* d_out, int out_size, void* d_ws, size_t ws_size,
                              hipStream_t stream) {
  const float* x     = (const float*)d_in[0];
  const float* w_qkv = (const float*)d_in[1];
  const float* b_qkv = (const float*)d_in[2];
  const float* w_o   = (const float*)d_in[3];
  const float* b_o   = (const float*)d_in[4];
  float* out = (float*)d_out;

  char* ws = (char*)d_ws;
  f16* xb    = (f16*)(ws);                 // [8192][512]        8.0 MiB
  f16* wqkvt = (f16*)(ws + 8388608);       // [1536][512]        1.5 MiB
  f16* wot   = (f16*)(ws + 9961472);       // [512][512]         0.5 MiB
  f16* Qs    = (f16*)(ws + 10485760);      // [16][4096][64]     8 MiB
  f16* Ks    = (f16*)(ws + 18874368);      // [16][4096][64]     8 MiB
  f16* Vs    = (f16*)(ws + 27262976);      // [16][4096][64]     8 MiB (row-major)
  f16* attn  = (f16*)(ws + 35651584);      // [8192][512]        8 MiB

  cast_f32_f16_kernel<<<4096, 256, 0, stream>>>(x, xb, 8192 * 512);
  transpose_cast_kernel<<<dim3(24, 8), 256, 0, stream>>>(w_qkv, wqkvt, 512, 1536);
  transpose_cast_kernel<<<dim3(8, 8), 256, 0, stream>>>(w_o, wot, 512, 512);
  gemm_bt_kernel<0, 128><<<dim3(64, 12), 256, 0, stream>>>(xb, wqkvt, b_qkv, Qs, Ks, Vs,
                                                           (float*)nullptr, 8192, 1536);
  attn_kernel<<<1024, 256, 0, stream>>>(Qs, Ks, Vs, attn);
  gemm_bt_kernel<1, 64><<<dim3(64, 8), 256, 0, stream>>>(attn, wot, b_o,
                                                         (f16*)nullptr, (f16*)nullptr, (f16*)nullptr,
                                                         out, 8192, 512);
}

// Round 10
// 66.623 us; speedup vs baseline: 1.6854x; 1.0118x over previous
//
#include <hip/hip_runtime.h>
#include <hip/hip_bf16.h>
#include <math.h>

typedef _Float16 f16;
typedef __attribute__((ext_vector_type(8))) _Float16 f16x8;
typedef __attribute__((ext_vector_type(4))) _Float16 f16x4;
typedef __attribute__((ext_vector_type(4))) float f32x4;

#define S_LEN 4096
#define NHEAD 8
#define HDIM 64
#define EMB 512
#define KDIM 512
#define LOG2E 1.4426950408889634f

#if __has_builtin(__builtin_amdgcn_exp2f)
#define EXP2F(x) __builtin_amdgcn_exp2f(x)
#else
#define EXP2F(x) exp2f(x)
#endif

// direct HBM->LDS 16B copy: lds dest = wave-uniform base (+ lane*16 by HW),
// global src is per-lane. CK-style addrspace casts (flat->AS3 = low-32 trunc).
__device__ __forceinline__ void g2l16(const void* g, void* l) {
  __builtin_amdgcn_global_load_lds(
      reinterpret_cast<const __attribute__((address_space(1))) unsigned int*>(
          reinterpret_cast<uintptr_t>(g)),
      reinterpret_cast<__attribute__((address_space(3))) unsigned int*>(
          static_cast<unsigned int>(reinterpret_cast<uintptr_t>(l))),
      16, 0, 0);
}

// ---------------- fused prep: x cast + w_qkv transpose + w_o transpose ----------------
// blocks [0,4096): cast x (f32->f16, float4/lane)
// blocks [4096,4288): transpose w_qkv 512x1536 -> [1536][512] f16  (24x8 tiles)
// blocks [4288,4352): transpose w_o   512x512  -> [512][512]  f16  (8x8 tiles)
__global__ __launch_bounds__(256) void prep_kernel(
    const float* __restrict__ x, f16* __restrict__ xb,
    const float* __restrict__ w_qkv, f16* __restrict__ wqkvt,
    const float* __restrict__ w_o, f16* __restrict__ wot) {
  __shared__ f16 tile[64][65];  // +1 pad: column reads conflict-free
  const int bid = blockIdx.x;
  const int tid = threadIdx.x;
  if (bid < 4096) {
    const int i = (bid * 256 + tid) * 4;
    float4 v = *(const float4*)(x + i);
    f16x4 o = { (f16)v.x, (f16)v.y, (f16)v.z, (f16)v.w };
    *(f16x4*)(xb + i) = o;
    return;
  }
  const float* in;
  f16* out;
  int R, C, c0, r0;
  if (bid < 4288) {
    const int t = bid - 4096;
    in = w_qkv; out = wqkvt; R = 512; C = 1536;
    c0 = (t % 24) * 64; r0 = (t / 24) * 64;
  } else {
    const int t = bid - 4288;
    in = w_o; out = wot; R = 512; C = 512;
    c0 = (t & 7) * 64; r0 = (t >> 3) * 64;
  }
#pragma unroll
  for (int i = 0; i < 16; ++i) {
    const int idx = i * 256 + tid;
    const int lr = idx >> 6, lc = idx & 63;
    tile[lr][lc] = (f16)in[(size_t)(r0 + lr) * C + (c0 + lc)];  // coalesced read
  }
  __syncthreads();
#pragma unroll
  for (int i = 0; i < 16; ++i) {
    const int idx = i * 256 + tid;
    const int lc = idx >> 6, lr = idx & 63;
    out[(size_t)(c0 + lc) * R + (r0 + lr)] = tile[lr][lc];      // coalesced write
  }
}

// ---------------- GEMM: C[M][N] = A[M][K] * Bt[N][K]^T + bias ----------------
// m97-style staging: global_load_lds dwordx4 into LINEAR LDS tiles, 2-barrier loop.
// TM fixed 128 (4 waves, 2x2 wave grid: rows wr*64, cols wc*(TN/2)).
#define TM 128
#define TK 32

template<int MODE, int TN>
__global__ __launch_bounds__(256) void gemm_bt_kernel(
    const f16* __restrict__ A, const f16* __restrict__ Bt, const float* __restrict__ bias,
    f16* __restrict__ Qo, f16* __restrict__ Ko, f16* __restrict__ Vo,
    float* __restrict__ Co, int M, int N) {
  constexpr int JN = TN / 32;    // B-frags / acc cols per wave
  constexpr int BCH = TN / 64;   // B staging chunks per wave
  __shared__ f16 As[TM][TK];     // linear: gload_lds dest contiguous in lane order
  __shared__ f16 Bs[TN][TK];
  const int m0 = blockIdx.x * TM, n0 = blockIdx.y * TN;
  const int tid = threadIdx.x;
  const int lane = tid & 63, wid = tid >> 6;
  const int wr = wid >> 1, wc = wid & 1;
  const int g = lane >> 4, q16 = lane & 15;

  // staging geometry: chunk = 16 rows = 1024 B; lane l -> row l>>2, 16B slot l&3.
  const int srow = lane >> 2;
  const int skof = (lane & 3) * 8;
  const f16* Ag[2]; char* Al[2];
#pragma unroll
  for (int cb = 0; cb < 2; ++cb) {
    const int ch = wid * 2 + cb;
    Ag[cb] = A + (size_t)(m0 + ch * 16 + srow) * KDIM + skof;
    Al[cb] = (char*)As + ch * 1024;
  }
  const f16* Bg[BCH]; char* Bl[BCH];
#pragma unroll
  for (int cb = 0; cb < BCH; ++cb) {
    const int ch = wid * BCH + cb;
    Bg[cb] = Bt + (size_t)(n0 + ch * 16 + srow) * KDIM + skof;
    Bl[cb] = (char*)Bs + ch * 1024;
  }

  f32x4 zero = {0.f, 0.f, 0.f, 0.f};
  f32x4 acc[4][JN];
#pragma unroll
  for (int i = 0; i < 4; i++)
#pragma unroll
    for (int j = 0; j < JN; j++) acc[i][j] = zero;

  for (int kk = 0; kk < KDIM; kk += TK) {
    g2l16(Ag[0] + kk, Al[0]);
    g2l16(Ag[1] + kk, Al[1]);
#pragma unroll
    for (int cb = 0; cb < BCH; ++cb) g2l16(Bg[cb] + kk, Bl[cb]);
    __syncthreads();   // drains vmcnt (gload_lds) + joins waves
    f16x8 af[4], bfr[JN];
#pragma unroll
    for (int i = 0; i < 4; i++) af[i] = *(const f16x8*)&As[wr * 64 + i * 16 + q16][8 * g];
#pragma unroll
    for (int j = 0; j < JN; j++) bfr[j] = *(const f16x8*)&Bs[wc * (TN / 2) + j * 16 + q16][8 * g];
#pragma unroll
    for (int i = 0; i < 4; i++)
#pragma unroll
      for (int j = 0; j < JN; j++)
        acc[i][j] = __builtin_amdgcn_mfma_f32_16x16x32_f16(af[i], bfr[j], acc[i][j], 0, 0, 0);
    __syncthreads();   // all ds_reads done before next-iter staging overwrites
  }

#pragma unroll
  for (int i = 0; i < 4; i++)
#pragma unroll
    for (int j = 0; j < JN; j++) {
      const int n = n0 + wc * (TN / 2) + j * 16 + q16;
      const float bs = bias[n];
      const int mbase = m0 + wr * 64 + i * 16 + 4 * g;
      if (MODE == 1) {
#pragma unroll
        for (int r = 0; r < 4; r++) Co[(size_t)(mbase + r) * N + n] = acc[i][j][r] + bs;
      } else {
        const int b = mbase >> 12, s = mbase & (S_LEN - 1);
        const int h = n / 192, rr = n - h * 192;
        const size_t bh = (size_t)b * NHEAD + h;
        if (rr < 64) {
#pragma unroll
          for (int r = 0; r < 4; r++)
            Qo[(bh * S_LEN + s + r) * HDIM + rr] = (f16)((acc[i][j][r] + bs) * 0.125f);
        } else if (rr < 128) {
#pragma unroll
          for (int r = 0; r < 4; r++)
            Ko[(bh * S_LEN + s + r) * HDIM + (rr - 64)] = (f16)(acc[i][j][r] + bs);
        } else {
#pragma unroll
          for (int r = 0; r < 4; r++)
            Vo[(bh * S_LEN + s + r) * HDIM + (rr - 128)] = (f16)(acc[i][j][r] + bs);  // V row-major
        }
      }
    }
}

// ---------------- sliding-window flash attention (LDS window) ----------------
// Q,K,V: [bh][s][64] f16 (Q pre-scaled by 1/8); out: [b][s][512] f16
// Block = 64 queries; stage 320-key K+V window in LDS (80 KB); 4 waves x 9 tiles pure-LDS.
// LDS map: Ks [0,40960): row r(0..319) pitch 128B, 16B slots XOR-swizzled by (r&7).
//          Vs [40960,81920): 128B block per (dt, 4-key group kg): byte(key',d) =
//            VSOFF + (d>>4)*10240 + (key'>>2)*128 + (key'&3)*32 + (d&15)*2
//          (4x16 row-major f16 matrix per block -> tr_b16 column reads)
#define VSOFF 40960

__global__ __launch_bounds__(256) void attn_kernel(
    const f16* __restrict__ Q, const f16* __restrict__ K,
    const f16* __restrict__ V, f16* __restrict__ O) {
  __shared__ __align__(16) char smem[81920];

  const int wg = blockIdx.x;
  const int vv = (wg & 7) * 128 + (wg >> 3);   // XCD swizzle (1024 % 8 == 0, bijective)
  const int bh = vv >> 6, qc = vv & 63;
  const int b = bh >> 3, h = bh & 7;
  const int tid = threadIdx.x;
  const int wid = tid >> 6, lane = tid & 63;
  const int g = lane >> 4, q16 = lane & 15;
  const int qb = qc * 64;          // block's first query
  const int wb = qb - 128;         // window base key (may be negative; staging clamps)
  const int qw = qb + wid * 16;    // this wave's 16 queries
  const int qg = qw + q16;

  const f16* Kb_g = K + (size_t)bh * S_LEN * HDIM;
  const f16* Vb_g = V + (size_t)bh * S_LEN * HDIM;

  // ---- stage K window: 320 rows x 64 dims, coalesced, XOR-swizzled 16B slots ----
#pragma unroll
  for (int rd = 0; rd < 10; ++rd) {
    const int idx = rd * 256 + tid;
    const int r = idx >> 3, sl = idx & 7;           // row, 16B slot (dims 8*sl..8*sl+7)
    const int key = min(max(wb + r, 0), S_LEN - 1); // clamped rows masked in compute
    int4 kvv = *(const int4*)(Kb_g + (size_t)key * HDIM + sl * 8);
    *(int4*)(smem + r * 128 + ((sl ^ (r & 7)) << 4)) = kvv;
  }
  // ---- stage V window into tr_b16-compatible subtiled layout ----
#pragma unroll
  for (int rd = 0; rd < 10; ++rd) {
    const int idx = rd * 256 + tid;
    const int r = idx >> 3, c8 = (idx & 7) * 8;     // key-row, dim start
    const int key = min(max(wb + r, 0), S_LEN - 1);
    int4 vvv = *(const int4*)(Vb_g + (size_t)key * HDIM + c8);
    *(int4*)(smem + VSOFF + (c8 >> 4) * 10240 + (r >> 2) * 128 + (r & 3) * 32 + ((c8 & 8) << 1)) = vvv;
  }
  __syncthreads();

  const f16* Qb = Q + ((size_t)bh * S_LEN + qw) * HDIM;
  f16x8 qf0 = *(const f16x8*)(Qb + q16 * HDIM + 8 * g);        // d 0..31
  f16x8 qf1 = *(const f16x8*)(Qb + q16 * HDIM + 32 + 8 * g);   // d 32..63

  f32x4 zero = {0.f, 0.f, 0.f, 0.f};
  f32x4 o[4];
#pragma unroll
  for (int dt = 0; dt < 4; dt++) o[dt] = zero;
  float m_run = 0.f;   // static base; vote-guarded rescale (round-4 scheme)
  float l_run = 0.f;

  // per-lane tr_b16 address term: lane (g,q16) reads COLUMN q16 of BLOCK (kc>>2)+g.
  const unsigned troff = (unsigned)(g * 128 + q16 * 8);

#pragma unroll
  for (int t = 0; t < 9; ++t) {
    const int kAp = wid * 16 + 32 * t;   // window coords of chunk A
    const int kBp = kAp + 16;            // chunk B (may be 320 for w=3,t=8: fully masked)
    // K fragments from swizzled LDS (rows kAp+q16 / kBp+q16; slots g, g+4)
    const int rrA = kAp + q16;
    const int rrB = kBp + q16;
    f16x8 ka0 = *(const f16x8*)(smem + rrA * 128 + (((g    ) ^ (rrA & 7)) << 4));
    f16x8 ka1 = *(const f16x8*)(smem + rrA * 128 + (((g + 4) ^ (rrA & 7)) << 4));
    f16x8 kb0 = *(const f16x8*)(smem + rrB * 128 + (((g    ) ^ (rrB & 7)) << 4));
    f16x8 kb1 = *(const f16x8*)(smem + rrB * 128 + (((g + 4) ^ (rrB & 7)) << 4));

    f32x4 sA = zero, sB = zero;
    __builtin_amdgcn_s_setprio(1);
    sA = __builtin_amdgcn_mfma_f32_16x16x32_f16(ka0, qf0, sA, 0, 0, 0);
    sA = __builtin_amdgcn_mfma_f32_16x16x32_f16(ka1, qf1, sA, 0, 0, 0);
    sB = __builtin_amdgcn_mfma_f32_16x16x32_f16(kb0, qf0, sB, 0, 0, 0);
    sB = __builtin_amdgcn_mfma_f32_16x16x32_f16(kb1, qf1, sB, 0, 0, 0);
    __builtin_amdgcn_s_setprio(0);

    // mask (window + range); lane-local max only
    float sv[8];
    float mx = -INFINITY;
#pragma unroll
    for (int i = 0; i < 4; i++) {
      const int kgA = wb + kAp + 4 * g + i;
      const int kgB = wb + kBp + 4 * g + i;
      const bool okA = ((unsigned)(kgA - qg + 128) <= 256u) && ((unsigned)kgA < S_LEN);
      const bool okB = ((unsigned)(kgB - qg + 128) <= 256u) && ((unsigned)kgB < S_LEN);
      sv[i]     = okA ? sA[i] : -INFINITY;
      sv[i + 4] = okB ? sB[i] : -INFINITY;
      mx = fmaxf(mx, fmaxf(sv[i], sv[i + 4]));
    }

    // speculative p = exp(sv - m_run); corrected on the (~never) cold path
    float pA[4], pB[4];
#pragma unroll
    for (int i = 0; i < 4; i++) {
      pA[i] = EXP2F((sv[i] - m_run) * LOG2E);
      pB[i] = EXP2F((sv[i + 4] - m_run) * LOG2E);
    }

    if (__builtin_expect(!__all(mx - m_run <= 8.f), 0)) {
      float mxq = fmaxf(mx, __shfl_xor(mx, 16));
      mxq = fmaxf(mxq, __shfl_xor(mxq, 32));
      const float mnew = fmaxf(m_run, mxq);
      const float resc = EXP2F((m_run - mnew) * LOG2E);   // per query q16
#pragma unroll
      for (int i = 0; i < 4; i++) { pA[i] *= resc; pB[i] *= resc; }
      l_run *= resc;
      float ri[4];
#pragma unroll
      for (int i = 0; i < 4; i++) ri[i] = __shfl(resc, 4 * g + i);
#pragma unroll
      for (int dt = 0; dt < 4; dt++)
#pragma unroll
        for (int i = 0; i < 4; i++) o[dt][i] *= ri[i];
      m_run = mnew;
    }

    f16x4 pfA, pfB;
#pragma unroll
    for (int i = 0; i < 4; i++) {
      l_run += pA[i] + pB[i];
      pfA[i] = (f16)pA[i];
      pfB[i] = (f16)pB[i];
    }

    // V B-fragments via LDS transpose-read: lane (g,q16) reads column q16 of
    // block (kc>>2)+g  ->  B[k=4g+j][n=q16] = V[kc+4g+j][dt*16+q16].
    const int kcA = kAp;
    const int kcB = min(kBp, 304);   // overflow tile is fully masked (pfB==0)
    f16x4 bA[4], bB[4];
#pragma unroll
    for (int dt = 0; dt < 4; ++dt) {
      unsigned aA = (unsigned)(uintptr_t)(smem + VSOFF + dt * 10240 + (kcA >> 2) * 128) + troff;
      unsigned aB = (unsigned)(uintptr_t)(smem + VSOFF + dt * 10240 + (kcB >> 2) * 128) + troff;
      asm volatile("ds_read_b64_tr_b16 %0, %1" : "=v"(bA[dt]) : "v"(aA));
      asm volatile("ds_read_b64_tr_b16 %0, %1" : "=v"(bB[dt]) : "v"(aB));
    }
    asm volatile("s_waitcnt lgkmcnt(0)" ::: "memory");
    __builtin_amdgcn_sched_barrier(0);

    __builtin_amdgcn_s_setprio(1);
#pragma unroll
    for (int dt = 0; dt < 4; dt++) {
      o[dt] = __builtin_amdgcn_mfma_f32_16x16x16f16(pfA, bA[dt], o[dt], 0, 0, 0);
      o[dt] = __builtin_amdgcn_mfma_f32_16x16x16f16(pfB, bB[dt], o[dt], 0, 0, 0);
    }
    __builtin_amdgcn_s_setprio(0);
  }

  // epilogue: reduce l across the 4 g-groups (same query), normalize
  l_run += __shfl_xor(l_run, 16);
  l_run += __shfl_xor(l_run, 32);
  const float linv = 1.f / l_run;
  float li[4];
#pragma unroll
  for (int i = 0; i < 4; i++) li[i] = __shfl(linv, 4 * g + i);

  // O-store via wave-private LDS bounce: 16 scattered 2B stores/lane ->
  // coalesced 2x16B stores/lane. Barrier first: all waves done reading K/V LDS.
  __syncthreads();
  float* st = (float*)smem + wid * 1024;   // 4 KB per wave
#pragma unroll
  for (int dt = 0; dt < 4; dt++)
#pragma unroll
    for (int i = 0; i < 4; i++)
      st[(4 * g + i) * 64 + dt * 16 + q16] = o[dt][i] * li[i];
  // (compiler inserts lgkmcnt wait between aliasing ds_write/ds_read)
  const int r = lane >> 2, c0 = (lane & 3) * 16;
  const float* sp = st + r * 64 + c0;
  f16x8 h0, h1;
#pragma unroll
  for (int j = 0; j < 8; j++) { h0[j] = (f16)sp[j]; h1[j] = (f16)sp[8 + j]; }
  f16* dst = O + ((size_t)b * S_LEN + qw + r) * EMB + h * HDIM + c0;
  *(f16x8*)dst = h0;
  *(f16x8*)(dst + 8) = h1;
}

// ---------------- launch ----------------
extern "C" void kernel_launch(void* const* d_in, const int* in_sizes, int n_in,
                              void* d_out, int out_size, void* d_ws, size_t ws_size,
                              hipStream_t stream) {
  const float* x     = (const float*)d_in[0];
  const float* w_qkv = (const float*)d_in[1];
  const float* b_qkv = (const float*)d_in[2];
  const float* w_o   = (const float*)d_in[3];
  const float* b_o   = (const float*)d_in[4];
  float* out = (float*)d_out;

  char* ws = (char*)d_ws;
  f16* xb    = (f16*)(ws);                 // [8192][512]        8.0 MiB
  f16* wqkvt = (f16*)(ws + 8388608);       // [1536][512]        1.5 MiB
  f16* wot   = (f16*)(ws + 9961472);       // [512][512]         0.5 MiB
  f16* Qs    = (f16*)(ws + 10485760);      // [16][4096][64]     8 MiB
  f16* Ks    = (f16*)(ws + 18874368);      // [16][4096][64]     8 MiB
  f16* Vs    = (f16*)(ws + 27262976);      // [16][4096][64]     8 MiB (row-major)
  f16* attn  = (f16*)(ws + 35651584);      // [8192][512]        8 MiB

  prep_kernel<<<4352, 256, 0, stream>>>(x, xb, w_qkv, wqkvt, w_o, wot);
  gemm_bt_kernel<0, 128><<<dim3(64, 12), 256, 0, stream>>>(xb, wqkvt, b_qkv, Qs, Ks, Vs,
                                                           (float*)nullptr, 8192, 1536);
  attn_kernel<<<1024, 256, 0, stream>>>(Qs, Ks, Vs, attn);
  gemm_bt_kernel<1, 64><<<dim3(64, 8), 256, 0, stream>>>(attn, wot, b_o,
                                                         (f16*)nullptr, (f16*)nullptr, (f16*)nullptr,
                                                         out, 8192, 512);
}